// Round 8
// baseline (836.877 us; speedup 1.0000x reference)
//
#include <hip/hip_runtime.h>
#include <hip/hip_bf16.h>

typedef unsigned short u16;
typedef __attribute__((ext_vector_type(8))) short bf16x8;
typedef __attribute__((ext_vector_type(4))) float f32x4;

#define DEVI __device__ __forceinline__

constexpr float SCALE = 0.125f;   // DH^-0.5, exact power of 2

DEVI float bf2f(u16 u) { unsigned v = ((unsigned)u) << 16; float f; __builtin_memcpy(&f, &v, 4); return f; }
DEVI u16 f2bf(float f) { __hip_bfloat16 h = __float2bfloat16(f); u16 u; __builtin_memcpy(&u, &h, 2); return u; }

// async global->LDS, 16B per lane. LDS dest is wave-uniform base + lane*16.
DEVI void gload_lds16(const u16* g, u16* l) {
    __builtin_amdgcn_global_load_lds(
        (const __attribute__((address_space(1))) unsigned int*)g,
        (__attribute__((address_space(3))) unsigned int*)l, 16, 0, 0);
}

// ---------------------------------------------------------------------------
// Cast fp32 -> bf16, 4 elems/thread.
// ---------------------------------------------------------------------------
__global__ __launch_bounds__(256) void cast_f32_bf16(const float* __restrict__ in,
                                                     u16* __restrict__ out, int n) {
    int i = (blockIdx.x * 256 + threadIdx.x) * 4;
    if (i >= n) return;
    float4 v = *(const float4*)(in + i);
    ushort4 o;
    o.x = f2bf(v.x); o.y = f2bf(v.y); o.z = f2bf(v.z); o.w = f2bf(v.w);
    *(ushort4*)(out + i) = o;
}

// ---------------------------------------------------------------------------
// Transpose + cast: in fp32 [R][C] -> out bf16 [C][R]. grid = (C/64, R/64).
// ---------------------------------------------------------------------------
__global__ __launch_bounds__(256) void transpose_f32_bf16(const float* __restrict__ in,
                                                          u16* __restrict__ out,
                                                          int R, int C) {
    __shared__ u16 t[64][65];
    int r0 = blockIdx.y * 64, c0 = blockIdx.x * 64;
    int tid = threadIdx.x;
    for (int i = 0; i < 16; i++) {
        int idx = tid + i * 256; int r = idx >> 6, c = idx & 63;
        t[r][c] = f2bf(in[(size_t)(r0 + r) * C + c0 + c]);
    }
    __syncthreads();
    for (int i = 0; i < 16; i++) {
        int idx = tid + i * 256; int c = idx >> 6, r = idx & 63;
        out[(size_t)(c0 + c) * R + r0 + r] = t[r][c];
    }
}

// ---------------------------------------------------------------------------
// Vt: qkv V-part [b,n,h,dh] -> vt[bh][dh][n].  grid = (16 n-tiles, 128 bh).
// ---------------------------------------------------------------------------
__global__ __launch_bounds__(256) void make_vt(const u16* __restrict__ qkv,
                                               u16* __restrict__ vt) {
    __shared__ u16 t[64][65];
    int bh = blockIdx.y; int b = bh >> 4, h = bh & 15;
    int n0 = blockIdx.x * 64;
    int tid = threadIdx.x;
    const u16* src = qkv + (size_t)b * 1024 * 3072 + 2048 + h * 64;
    for (int i = 0; i < 16; i++) {
        int idx = tid + i * 256; int n = idx >> 6, d = idx & 63;
        t[n][d] = src[(size_t)(n0 + n) * 3072 + d];
    }
    __syncthreads();
    u16* dst = vt + (size_t)bh * 64 * 1024;
    for (int i = 0; i < 16; i++) {
        int idx = tid + i * 256; int d = idx >> 6, n = idx & 63;
        dst[(size_t)d * 1024 + n0 + n] = t[n][d];
    }
}

// ---------------------------------------------------------------------------
// GEMM: C[M][N] = A[M][K] @ Bt[N][K]^T (+fp32 bias). A,Bt bf16; C bf16 or f32.
// m97 structure: 128x128 tile, BK=64, 4 waves, LINEAR LDS [128][64],
// staging via global_load_lds width=16 (ladder-verified 874 TF vs 517).
// ---------------------------------------------------------------------------
template <bool BIAS, bool F32OUT>
__global__ __launch_bounds__(256) void gemm_bt(const u16* __restrict__ A,
                                               const u16* __restrict__ Bt,
                                               const float* __restrict__ bias,
                                               void* __restrict__ Cv,
                                               int M, int N, int K) {
    __shared__ alignas(16) u16 As[128 * 64];
    __shared__ alignas(16) u16 Bs[128 * 64];
    int tid = threadIdx.x;
    int wave = tid >> 6, lane = tid & 63, quad = lane >> 4, lm = lane & 15;
    int bm = blockIdx.y * 128, bn = blockIdx.x * 128;
    int wm = (wave >> 1) * 64, wn = (wave & 1) * 64;

    f32x4 acc[4][4];
    for (int i = 0; i < 4; i++) for (int j = 0; j < 4; j++) acc[i][j] = f32x4{0.f, 0.f, 0.f, 0.f};

    // per-lane staging geometry: chunk c covers rows c*8..c*8+7, 128B/row
    int lrow8 = lane >> 3;        // row within chunk
    int lcol  = (lane & 7) * 8;   // u16 offset within row

    for (int kb = 0; kb < K; kb += 64) {
        for (int i = 0; i < 4; i++) {
            int c = wave * 4 + i;           // 16 chunks of 8 rows
            int row = c * 8 + lrow8;
            gload_lds16(A  + (size_t)(bm + row) * K + kb + lcol, &As[c * 512 + lane * 8]);
            gload_lds16(Bt + (size_t)(bn + row) * K + kb + lcol, &Bs[c * 512 + lane * 8]);
        }
        __syncthreads();   // barrier drain waits vmcnt(0): LDS tiles complete
        for (int ks = 0; ks < 2; ks++) {
            bf16x8 af[4], bfr[4];
            for (int mt = 0; mt < 4; mt++)
                af[mt] = *(const bf16x8*)(&As[(wm + mt * 16 + lm) * 64 + ks * 32 + quad * 8]);
            for (int nt = 0; nt < 4; nt++)
                bfr[nt] = *(const bf16x8*)(&Bs[(wn + nt * 16 + lm) * 64 + ks * 32 + quad * 8]);
            for (int mt = 0; mt < 4; mt++)
                for (int nt = 0; nt < 4; nt++)
                    acc[mt][nt] = __builtin_amdgcn_mfma_f32_16x16x32_bf16(
                        af[mt], bfr[nt], acc[mt][nt], 0, 0, 0);
        }
        __syncthreads();
    }
    for (int mt = 0; mt < 4; mt++)
        for (int nt = 0; nt < 4; nt++) {
            int col = bn + wn + nt * 16 + lm;
            float bv = BIAS ? bias[col] : 0.f;
            for (int r = 0; r < 4; r++) {
                int row = bm + wm + mt * 16 + quad * 4 + r;
                if (F32OUT) ((float*)Cv)[(size_t)row * N + col] = acc[mt][nt][r] + bv;
                else        ((u16*)Cv)[(size_t)row * N + col] = f2bf(acc[mt][nt][r] + bv);
            }
        }
}

// ---------------------------------------------------------------------------
// MFMA attention: grid (16,128) XCD-swizzled, 4 waves x 16 q-rows.
// K/V DOUBLE-BUFFERED with ONE barrier per tile (prefetch of tile kb+1 issued
// right after the barrier -> staging latency hides under tile kb's MFMA+exp),
// and XOR-SWIZZLED K/V LDS layout (rule 21: swizzle the global source col for
// gload_lds + same involution on fragment reads): byte bits[6:4] ^= row&7 ->
// fragment ds_read_b128 16-way -> 2-way (free).
// Ps stays padded + wave-private (no barrier between write and read).
// ---------------------------------------------------------------------------
__global__ __launch_bounds__(256) void attn_mfma(const u16* __restrict__ qkv,
                                                 const u16* __restrict__ vt,
                                                 const int* __restrict__ mask,
                                                 float* __restrict__ attn_out,
                                                 u16* __restrict__ o_ws) {
    __shared__ alignas(16) u16 Ks[2 * 64 * 64];   // 16 KB (2 bufs)
    __shared__ alignas(16) u16 Vs[2 * 64 * 64];   // 16 KB
    constexpr int LDP = 72;                       // Ps pad: 144B stride, 2-way
    __shared__ alignas(16) u16 Ps[64 * LDP];      // 9 KB

    int tid = threadIdx.x;
    int wave = tid >> 6, lane = tid & 63, quad = lane >> 4, lm = lane & 15;

    // XCD-aware swizzle (bijective, 2048 = 8*256): one head's 16 q-blocks
    // land on one XCD -> its K/V (256KB) stays in that XCD's L2.
    int flat = blockIdx.y * gridDim.x + blockIdx.x;
    int swz = (flat & 7) * 256 + (flat >> 3);
    int bh = swz >> 4, qb = swz & 15;
    int b = bh >> 4, h = bh & 15;
    int qrow0 = qb * 64 + wave * 16;

    // staging geometry: chunk c = 8 rows x 128B; per-lane swizzled source col
    int srow = lane >> 3;                          // row within 8-row chunk
    int scol = (((lane & 7) ^ srow) << 3);         // XOR-swizzled u16 col

    const u16* kbase  = qkv + (size_t)b * 1024 * 3072 + 1024 + h * 64;  // K[n][dh], stride 3072
    const u16* vtbase = vt + (size_t)bh * 64 * 1024;                    // V^T[dh][n], stride 1024
    const int* mrow   = mask + b * 1024;

    // prologue sweep 1: stage K(0) -> buf0 (overlaps Q load below)
    for (int i = 0; i < 2; i++) {
        int c = wave * 2 + i;
        gload_lds16(kbase + (size_t)(c * 8 + srow) * 3072 + scol, &Ks[c * 512 + lane * 8]);
    }

    // Q fragments for this wave's 16 rows (held in regs for whole kernel)
    bf16x8 qf[2];
    {
        const u16* qptr = qkv + (size_t)(b * 1024 + qrow0 + lm) * 3072 + h * 64 + quad * 8;
        qf[0] = *(const bf16x8*)(qptr);
        qf[1] = *(const bf16x8*)(qptr + 32);
    }

    // swizzled fragment-read cols (byte bits[6:4] ^= lm&7), hoisted per ks
    int fsw0 = ((0 * 4 + quad) ^ (lm & 7)) << 3;   // ks=0
    int fsw1 = ((1 * 4 + quad) ^ (lm & 7)) << 3;   // ks=1

    // ---- sweep 1: row sum of exp(s); 1 barrier per tile, dbuf prefetch ----
    float l_r[4] = {0.f, 0.f, 0.f, 0.f};
    int cur = 0;
    for (int kb = 0; kb < 16; kb++) {
        __syncthreads();                 // drains vmcnt: K(kb) in buf[cur] ready
        if (kb < 15) {
            int nb = (cur ^ 1) * 4096;
            for (int i = 0; i < 2; i++) {
                int c = wave * 2 + i;
                gload_lds16(kbase + (size_t)((kb + 1) * 64 + c * 8 + srow) * 3072 + scol,
                            &Ks[nb + c * 512 + lane * 8]);
            }
        }
        const u16* K0 = &Ks[cur * 4096];
        f32x4 acc[4];
        for (int nt = 0; nt < 4; nt++) acc[nt] = f32x4{0.f, 0.f, 0.f, 0.f};
        for (int nt = 0; nt < 4; nt++) {
            bf16x8 kf0 = *(const bf16x8*)(&K0[(nt * 16 + lm) * 64 + fsw0]);
            bf16x8 kf1 = *(const bf16x8*)(&K0[(nt * 16 + lm) * 64 + fsw1]);
            acc[nt] = __builtin_amdgcn_mfma_f32_16x16x32_bf16(qf[0], kf0, acc[nt], 0, 0, 0);
            acc[nt] = __builtin_amdgcn_mfma_f32_16x16x32_bf16(qf[1], kf1, acc[nt], 0, 0, 0);
        }
        for (int nt = 0; nt < 4; nt++) {
            bool mk = (mrow[kb * 64 + nt * 16 + lm] != 0);
            for (int r = 0; r < 4; r++)
                l_r[r] += mk ? __expf(acc[nt][r] * SCALE) : 0.f;
        }
        cur ^= 1;
    }
    float invl[4];
    for (int r = 0; r < 4; r++) {
        float l = l_r[r];
        for (int s = 8; s >= 1; s >>= 1) l += __shfl_xor(l, s, 64);
        invl[r] = 1.0f / l;
    }

    // prologue sweep 2: stage K(0),V(0) -> buf0 (sweep-1 tail reads buf1: safe)
    for (int i = 0; i < 2; i++) {
        int c = wave * 2 + i;
        gload_lds16(kbase + (size_t)(c * 8 + srow) * 3072 + scol, &Ks[c * 512 + lane * 8]);
        gload_lds16(vtbase + (size_t)(c * 8 + srow) * 1024 + scol, &Vs[c * 512 + lane * 8]);
    }

    // ---- sweep 2: recompute scores, write P, O += P.V; 1 barrier/tile ----
    f32x4 oacc[4];
    for (int nt = 0; nt < 4; nt++) oacc[nt] = f32x4{0.f, 0.f, 0.f, 0.f};
    cur = 0;
    for (int kb = 0; kb < 16; kb++) {
        __syncthreads();                 // K(kb),V(kb) in buf[cur] ready
        if (kb < 15) {
            int nb = (cur ^ 1) * 4096;
            for (int i = 0; i < 2; i++) {
                int c = wave * 2 + i;
                gload_lds16(kbase + (size_t)((kb + 1) * 64 + c * 8 + srow) * 3072 + scol,
                            &Ks[nb + c * 512 + lane * 8]);
                gload_lds16(vtbase + (size_t)(c * 8 + srow) * 1024 + (kb + 1) * 64 + scol,
                            &Vs[nb + c * 512 + lane * 8]);
            }
        }
        const u16* K0 = &Ks[cur * 4096];
        const u16* V0 = &Vs[cur * 4096];
        f32x4 acc[4];
        for (int nt = 0; nt < 4; nt++) acc[nt] = f32x4{0.f, 0.f, 0.f, 0.f};
        for (int nt = 0; nt < 4; nt++) {
            bf16x8 kf0 = *(const bf16x8*)(&K0[(nt * 16 + lm) * 64 + fsw0]);
            bf16x8 kf1 = *(const bf16x8*)(&K0[(nt * 16 + lm) * 64 + fsw1]);
            acc[nt] = __builtin_amdgcn_mfma_f32_16x16x32_bf16(qf[0], kf0, acc[nt], 0, 0, 0);
            acc[nt] = __builtin_amdgcn_mfma_f32_16x16x32_bf16(qf[1], kf1, acc[nt], 0, 0, 0);
        }
        // P: attn stores issued first (retire during PV), then Ps for PV
        for (int nt = 0; nt < 4; nt++) {
            bool mk = (mrow[kb * 64 + nt * 16 + lm] != 0);
            for (int r = 0; r < 4; r++) {
                float p = mk ? __expf(acc[nt][r] * SCALE) * invl[r] : 0.f;
                attn_out[((size_t)bh * 1024 + qb * 64 + wave * 16 + quad * 4 + r) * 1024
                         + kb * 64 + nt * 16 + lm] = p;
                Ps[(wave * 16 + quad * 4 + r) * LDP + nt * 16 + lm] = f2bf(p);
            }
        }
        // O += P.V  (Ps rows wave-private: write->read same wave, in-order DS)
        for (int ks = 0; ks < 2; ks++) {
            bf16x8 pf = *(const bf16x8*)(&Ps[(wave * 16 + lm) * LDP + ks * 32 + quad * 8]);
            int fsw = (ks == 0) ? fsw0 : fsw1;
            for (int nt = 0; nt < 4; nt++) {
                bf16x8 vf = *(const bf16x8*)(&V0[(nt * 16 + lm) * 64 + fsw]);
                oacc[nt] = __builtin_amdgcn_mfma_f32_16x16x32_bf16(pf, vf, oacc[nt], 0, 0, 0);
            }
        }
        cur ^= 1;
    }
    // O -> ws as [b, n, h*dh]
    for (int nt = 0; nt < 4; nt++)
        for (int r = 0; r < 4; r++) {
            int row = qb * 64 + wave * 16 + quad * 4 + r;
            o_ws[(size_t)(b * 1024 + row) * 1024 + h * 64 + nt * 16 + lm] = f2bf(oacc[nt][r]);
        }
}

// ---------------------------------------------------------------------------
extern "C" void kernel_launch(void* const* d_in, const int* in_sizes, int n_in,
                              void* d_out, int out_size, void* d_ws, size_t ws_size,
                              hipStream_t stream) {
    const float* x    = (const float*)d_in[0];   // fp32 per reference
    const int*   mask = (const int*)d_in[1];
    const float* wqkv = (const float*)d_in[2];
    const float* wout = (const float*)d_in[3];
    const float* bout = (const float*)d_in[4];

    float* out  = (float*)d_out;                    // [8192][1024] fp32
    float* attn = out + (size_t)8192 * 1024;        // [128][1024][1024] fp32

    // workspace layout (~92 MB). vt aliases xbf (xbf dead after gemm_qkv).
    char* ws = (char*)d_ws;
    u16* xbf   = (u16*)(ws);                        // 16,777,216 B
    u16* vt    = xbf;                               // reuse after gemm_qkv
    u16* qkv   = (u16*)(ws + 16777216);             // 50,331,648 B
    u16* o_ws  = (u16*)(ws + 67108864);             // 16,777,216 B
    u16* wqkvT = (u16*)(ws + 83886080);             //  6,291,456 B
    u16* woutT = (u16*)(ws + 90177536);             //  2,097,152 B

    cast_f32_bf16<<<dim3(8192), 256, 0, stream>>>(x, xbf, 8388608);
    transpose_f32_bf16<<<dim3(48, 16), 256, 0, stream>>>(wqkv, wqkvT, 1024, 3072);
    transpose_f32_bf16<<<dim3(16, 16), 256, 0, stream>>>(wout, woutT, 1024, 1024);
    gemm_bt<false, false><<<dim3(24, 64), 256, 0, stream>>>(xbf, wqkvT, nullptr, qkv, 8192, 3072, 1024);
    make_vt<<<dim3(16, 128), 256, 0, stream>>>(qkv, vt);
    attn_mfma<<<dim3(16, 128), 256, 0, stream>>>(qkv, vt, mask, attn, o_ws);
    gemm_bt<true, true><<<dim3(8, 64), 256, 0, stream>>>(o_ws, woutT, bout, out, 8192, 1024, 1024);
}

// Round 9
// 822.744 us; speedup vs baseline: 1.0172x; 1.0172x over previous
//
#include <hip/hip_runtime.h>
#include <hip/hip_bf16.h>

typedef unsigned short u16;
typedef __attribute__((ext_vector_type(8))) short bf16x8;
typedef __attribute__((ext_vector_type(4))) float f32x4;

#define DEVI __device__ __forceinline__

constexpr float SCALE = 0.125f;   // DH^-0.5, exact power of 2

DEVI float bf2f(u16 u) { unsigned v = ((unsigned)u) << 16; float f; __builtin_memcpy(&f, &v, 4); return f; }
DEVI u16 f2bf(float f) { __hip_bfloat16 h = __float2bfloat16(f); u16 u; __builtin_memcpy(&u, &h, 2); return u; }

// async global->LDS, 16B per lane. LDS dest is wave-uniform base + lane*16.
DEVI void gload_lds16(const u16* g, u16* l) {
    __builtin_amdgcn_global_load_lds(
        (const __attribute__((address_space(1))) unsigned int*)g,
        (__attribute__((address_space(3))) unsigned int*)l, 16, 0, 0);
}

// ---------------------------------------------------------------------------
// Cast fp32 -> bf16, 4 elems/thread.
// ---------------------------------------------------------------------------
__global__ __launch_bounds__(256) void cast_f32_bf16(const float* __restrict__ in,
                                                     u16* __restrict__ out, int n) {
    int i = (blockIdx.x * 256 + threadIdx.x) * 4;
    if (i >= n) return;
    float4 v = *(const float4*)(in + i);
    ushort4 o;
    o.x = f2bf(v.x); o.y = f2bf(v.y); o.z = f2bf(v.z); o.w = f2bf(v.w);
    *(ushort4*)(out + i) = o;
}

// ---------------------------------------------------------------------------
// Transpose + cast: in fp32 [R][C] -> out bf16 [C][R]. grid = (C/64, R/64).
// ---------------------------------------------------------------------------
__global__ __launch_bounds__(256) void transpose_f32_bf16(const float* __restrict__ in,
                                                          u16* __restrict__ out,
                                                          int R, int C) {
    __shared__ u16 t[64][65];
    int r0 = blockIdx.y * 64, c0 = blockIdx.x * 64;
    int tid = threadIdx.x;
    for (int i = 0; i < 16; i++) {
        int idx = tid + i * 256; int r = idx >> 6, c = idx & 63;
        t[r][c] = f2bf(in[(size_t)(r0 + r) * C + c0 + c]);
    }
    __syncthreads();
    for (int i = 0; i < 16; i++) {
        int idx = tid + i * 256; int c = idx >> 6, r = idx & 63;
        out[(size_t)(c0 + c) * R + r0 + r] = t[r][c];
    }
}

// ---------------------------------------------------------------------------
// Vt: qkv V-part [b,n,h,dh] -> vt[bh][dh][n].  grid = (16 n-tiles, 128 bh).
// ---------------------------------------------------------------------------
__global__ __launch_bounds__(256) void make_vt(const u16* __restrict__ qkv,
                                               u16* __restrict__ vt) {
    __shared__ u16 t[64][65];
    int bh = blockIdx.y; int b = bh >> 4, h = bh & 15;
    int n0 = blockIdx.x * 64;
    int tid = threadIdx.x;
    const u16* src = qkv + (size_t)b * 1024 * 3072 + 2048 + h * 64;
    for (int i = 0; i < 16; i++) {
        int idx = tid + i * 256; int n = idx >> 6, d = idx & 63;
        t[n][d] = src[(size_t)(n0 + n) * 3072 + d];
    }
    __syncthreads();
    u16* dst = vt + (size_t)bh * 64 * 1024;
    for (int i = 0; i < 16; i++) {
        int idx = tid + i * 256; int d = idx >> 6, n = idx & 63;
        dst[(size_t)d * 1024 + n0 + n] = t[n][d];
    }
}

// ---------------------------------------------------------------------------
// GEMM: C[M][N] = A[M][K] @ Bt[N][K]^T (+fp32 bias). A,Bt bf16; C bf16 or f32.
// m97 structure: 128x128 tile, BK=64, 4 waves, LINEAR LDS [128][64],
// staging via global_load_lds width=16 (ladder-verified 874 TF vs 517).
// ---------------------------------------------------------------------------
template <bool BIAS, bool F32OUT>
__global__ __launch_bounds__(256) void gemm_bt(const u16* __restrict__ A,
                                               const u16* __restrict__ Bt,
                                               const float* __restrict__ bias,
                                               void* __restrict__ Cv,
                                               int M, int N, int K) {
    __shared__ alignas(16) u16 As[128 * 64];
    __shared__ alignas(16) u16 Bs[128 * 64];
    int tid = threadIdx.x;
    int wave = tid >> 6, lane = tid & 63, quad = lane >> 4, lm = lane & 15;
    int bm = blockIdx.y * 128, bn = blockIdx.x * 128;
    int wm = (wave >> 1) * 64, wn = (wave & 1) * 64;

    f32x4 acc[4][4];
    for (int i = 0; i < 4; i++) for (int j = 0; j < 4; j++) acc[i][j] = f32x4{0.f, 0.f, 0.f, 0.f};

    // per-lane staging geometry: chunk c covers rows c*8..c*8+7, 128B/row
    int lrow8 = lane >> 3;        // row within chunk
    int lcol  = (lane & 7) * 8;   // u16 offset within row

    for (int kb = 0; kb < K; kb += 64) {
        for (int i = 0; i < 4; i++) {
            int c = wave * 4 + i;           // 16 chunks of 8 rows
            int row = c * 8 + lrow8;
            gload_lds16(A  + (size_t)(bm + row) * K + kb + lcol, &As[c * 512 + lane * 8]);
            gload_lds16(Bt + (size_t)(bn + row) * K + kb + lcol, &Bs[c * 512 + lane * 8]);
        }
        __syncthreads();   // barrier drain waits vmcnt(0): LDS tiles complete
        for (int ks = 0; ks < 2; ks++) {
            bf16x8 af[4], bfr[4];
            for (int mt = 0; mt < 4; mt++)
                af[mt] = *(const bf16x8*)(&As[(wm + mt * 16 + lm) * 64 + ks * 32 + quad * 8]);
            for (int nt = 0; nt < 4; nt++)
                bfr[nt] = *(const bf16x8*)(&Bs[(wn + nt * 16 + lm) * 64 + ks * 32 + quad * 8]);
            for (int mt = 0; mt < 4; mt++)
                for (int nt = 0; nt < 4; nt++)
                    acc[mt][nt] = __builtin_amdgcn_mfma_f32_16x16x32_bf16(
                        af[mt], bfr[nt], acc[mt][nt], 0, 0, 0);
        }
        __syncthreads();
    }
    for (int mt = 0; mt < 4; mt++)
        for (int nt = 0; nt < 4; nt++) {
            int col = bn + wn + nt * 16 + lm;
            float bv = BIAS ? bias[col] : 0.f;
            for (int r = 0; r < 4; r++) {
                int row = bm + wm + mt * 16 + quad * 4 + r;
                if (F32OUT) ((float*)Cv)[(size_t)row * N + col] = acc[mt][nt][r] + bv;
                else        ((u16*)Cv)[(size_t)row * N + col] = f2bf(acc[mt][nt][r] + bv);
            }
        }
}

// ---------------------------------------------------------------------------
// attn_lsum: sweep 1 alone. grid (16,128) XCD-swizzled, 4 waves.
// Only K dbuf in LDS (16 KB) -> wave-capped 8 blocks/CU (~100% occupancy).
// Writes invl[bh][1024] fp32 (aliases dead wqkvT region).
// ---------------------------------------------------------------------------
__global__ __launch_bounds__(256) void attn_lsum(const u16* __restrict__ qkv,
                                                 const int* __restrict__ mask,
                                                 float* __restrict__ invl_ws) {
    __shared__ alignas(16) u16 Ks[2 * 64 * 64];   // 16 KB

    int tid = threadIdx.x;
    int wave = tid >> 6, lane = tid & 63, quad = lane >> 4, lm = lane & 15;

    int flat = blockIdx.y * gridDim.x + blockIdx.x;
    int swz = (flat & 7) * 256 + (flat >> 3);
    int bh = swz >> 4, qb = swz & 15;
    int b = bh >> 4, h = bh & 15;
    int qrow0 = qb * 64 + wave * 16;

    int srow = lane >> 3;
    int scol = (((lane & 7) ^ srow) << 3);        // XOR-swizzled source col

    const u16* kbase = qkv + (size_t)b * 1024 * 3072 + 1024 + h * 64;
    const int* mrow  = mask + b * 1024;

    // prologue: stage K(0) -> buf0
    for (int i = 0; i < 2; i++) {
        int c = wave * 2 + i;
        gload_lds16(kbase + (size_t)(c * 8 + srow) * 3072 + scol, &Ks[c * 512 + lane * 8]);
    }

    bf16x8 qf[2];
    {
        const u16* qptr = qkv + (size_t)(b * 1024 + qrow0 + lm) * 3072 + h * 64 + quad * 8;
        qf[0] = *(const bf16x8*)(qptr);
        qf[1] = *(const bf16x8*)(qptr + 32);
    }
    int fsw0 = ((0 * 4 + quad) ^ (lm & 7)) << 3;
    int fsw1 = ((1 * 4 + quad) ^ (lm & 7)) << 3;

    float l_r[4] = {0.f, 0.f, 0.f, 0.f};
    int cur = 0;
    for (int kb = 0; kb < 16; kb++) {
        __syncthreads();
        if (kb < 15) {
            int nb = (cur ^ 1) * 4096;
            for (int i = 0; i < 2; i++) {
                int c = wave * 2 + i;
                gload_lds16(kbase + (size_t)((kb + 1) * 64 + c * 8 + srow) * 3072 + scol,
                            &Ks[nb + c * 512 + lane * 8]);
            }
        }
        const u16* K0 = &Ks[cur * 4096];
        f32x4 acc[4];
        for (int nt = 0; nt < 4; nt++) acc[nt] = f32x4{0.f, 0.f, 0.f, 0.f};
        for (int nt = 0; nt < 4; nt++) {
            bf16x8 kf0 = *(const bf16x8*)(&K0[(nt * 16 + lm) * 64 + fsw0]);
            bf16x8 kf1 = *(const bf16x8*)(&K0[(nt * 16 + lm) * 64 + fsw1]);
            acc[nt] = __builtin_amdgcn_mfma_f32_16x16x32_bf16(qf[0], kf0, acc[nt], 0, 0, 0);
            acc[nt] = __builtin_amdgcn_mfma_f32_16x16x32_bf16(qf[1], kf1, acc[nt], 0, 0, 0);
        }
        for (int nt = 0; nt < 4; nt++) {
            bool mk = (mrow[kb * 64 + nt * 16 + lm] != 0);
            for (int r = 0; r < 4; r++)
                l_r[r] += mk ? __expf(acc[nt][r] * SCALE) : 0.f;
        }
        cur ^= 1;
    }
    // butterfly over the 16 lanes of each quad group -> full row sums
    for (int r = 0; r < 4; r++)
        for (int s = 8; s >= 1; s >>= 1) l_r[r] += __shfl_xor(l_r[r], s, 64);
    if (lm == 0) {
        float4 v; v.x = 1.f / l_r[0]; v.y = 1.f / l_r[1]; v.z = 1.f / l_r[2]; v.w = 1.f / l_r[3];
        *(float4*)(invl_ws + (size_t)bh * 1024 + qb * 64 + wave * 16 + quad * 4) = v;
    }
}

// ---------------------------------------------------------------------------
// attn_pv: sweep 2 alone. grid (16,128) XCD-swizzled, 4 waves.
// K/V dbuf (32 KB) + Ps linear [64][64] XOR-swizzled (8 KB) = 40960 B exactly
// -> 4 blocks/CU. Reads invl from ws; writes P fp32 to attn, O bf16 to o_ws.
// Ps swizzle: write idx ^= ((pr&7)<<3), read idx ^= ((lm&7)<<3) (u16 units;
// 16B-aligned granule -> b128 reads legal; wave-private rows preserved).
// ---------------------------------------------------------------------------
__global__ __launch_bounds__(256) void attn_pv(const u16* __restrict__ qkv,
                                               const u16* __restrict__ vt,
                                               const int* __restrict__ mask,
                                               const float* __restrict__ invl_ws,
                                               float* __restrict__ attn_out,
                                               u16* __restrict__ o_ws) {
    __shared__ alignas(16) u16 Ks[2 * 64 * 64];   // 16 KB
    __shared__ alignas(16) u16 Vs[2 * 64 * 64];   // 16 KB
    __shared__ alignas(16) u16 Ps[64 * 64];       // 8 KB (XOR-swizzled)

    int tid = threadIdx.x;
    int wave = tid >> 6, lane = tid & 63, quad = lane >> 4, lm = lane & 15;

    int flat = blockIdx.y * gridDim.x + blockIdx.x;
    int swz = (flat & 7) * 256 + (flat >> 3);
    int bh = swz >> 4, qb = swz & 15;
    int b = bh >> 4, h = bh & 15;
    int qrow0 = qb * 64 + wave * 16;

    int srow = lane >> 3;
    int scol = (((lane & 7) ^ srow) << 3);

    const u16* kbase  = qkv + (size_t)b * 1024 * 3072 + 1024 + h * 64;
    const u16* vtbase = vt + (size_t)bh * 64 * 1024;
    const int* mrow   = mask + b * 1024;

    // prologue: stage K(0),V(0) -> buf0
    for (int i = 0; i < 2; i++) {
        int c = wave * 2 + i;
        gload_lds16(kbase + (size_t)(c * 8 + srow) * 3072 + scol, &Ks[c * 512 + lane * 8]);
        gload_lds16(vtbase + (size_t)(c * 8 + srow) * 1024 + scol, &Vs[c * 512 + lane * 8]);
    }

    bf16x8 qf[2];
    {
        const u16* qptr = qkv + (size_t)(b * 1024 + qrow0 + lm) * 3072 + h * 64 + quad * 8;
        qf[0] = *(const bf16x8*)(qptr);
        qf[1] = *(const bf16x8*)(qptr + 32);
    }
    float invl[4];
    for (int r = 0; r < 4; r++)
        invl[r] = invl_ws[(size_t)bh * 1024 + qrow0 + quad * 4 + r];

    int fsw0 = ((0 * 4 + quad) ^ (lm & 7)) << 3;
    int fsw1 = ((1 * 4 + quad) ^ (lm & 7)) << 3;
    int psw  = (lm & 7) << 3;                      // Ps read xor (u16 units)

    f32x4 oacc[4];
    for (int nt = 0; nt < 4; nt++) oacc[nt] = f32x4{0.f, 0.f, 0.f, 0.f};
    int cur = 0;
    for (int kb = 0; kb < 16; kb++) {
        __syncthreads();                 // K(kb),V(kb) in buf[cur] ready
        if (kb < 15) {
            int nb = (cur ^ 1) * 4096;
            for (int i = 0; i < 2; i++) {
                int c = wave * 2 + i;
                gload_lds16(kbase + (size_t)((kb + 1) * 64 + c * 8 + srow) * 3072 + scol,
                            &Ks[nb + c * 512 + lane * 8]);
                gload_lds16(vtbase + (size_t)(c * 8 + srow) * 1024 + (kb + 1) * 64 + scol,
                            &Vs[nb + c * 512 + lane * 8]);
            }
        }
        const u16* K0 = &Ks[cur * 4096];
        const u16* V0 = &Vs[cur * 4096];
        f32x4 acc[4];
        for (int nt = 0; nt < 4; nt++) acc[nt] = f32x4{0.f, 0.f, 0.f, 0.f};
        for (int nt = 0; nt < 4; nt++) {
            bf16x8 kf0 = *(const bf16x8*)(&K0[(nt * 16 + lm) * 64 + fsw0]);
            bf16x8 kf1 = *(const bf16x8*)(&K0[(nt * 16 + lm) * 64 + fsw1]);
            acc[nt] = __builtin_amdgcn_mfma_f32_16x16x32_bf16(qf[0], kf0, acc[nt], 0, 0, 0);
            acc[nt] = __builtin_amdgcn_mfma_f32_16x16x32_bf16(qf[1], kf1, acc[nt], 0, 0, 0);
        }
        for (int nt = 0; nt < 4; nt++) {
            bool mk = (mrow[kb * 64 + nt * 16 + lm] != 0);
            for (int r = 0; r < 4; r++) {
                float p = mk ? __expf(acc[nt][r] * SCALE) * invl[r] : 0.f;
                attn_out[((size_t)bh * 1024 + qb * 64 + wave * 16 + quad * 4 + r) * 1024
                         + kb * 64 + nt * 16 + lm] = p;
                int pr = wave * 16 + quad * 4 + r;
                int pidx = (pr * 64 + nt * 16 + lm) ^ (((quad * 4 + r) & 7) << 3);
                Ps[pidx] = f2bf(p);
            }
        }
        // O += P.V  (Ps rows wave-private: same-wave write->read, in-order DS)
        for (int ks = 0; ks < 2; ks++) {
            int ridx = ((wave * 16 + lm) * 64 + ks * 32 + quad * 8) ^ psw;
            bf16x8 pf = *(const bf16x8*)(&Ps[ridx]);
            int fsw = (ks == 0) ? fsw0 : fsw1;
            for (int nt = 0; nt < 4; nt++) {
                bf16x8 vf = *(const bf16x8*)(&V0[(nt * 16 + lm) * 64 + fsw]);
                oacc[nt] = __builtin_amdgcn_mfma_f32_16x16x32_bf16(pf, vf, oacc[nt], 0, 0, 0);
            }
        }
        cur ^= 1;
    }
    for (int nt = 0; nt < 4; nt++)
        for (int r = 0; r < 4; r++) {
            int row = qb * 64 + wave * 16 + quad * 4 + r;
            o_ws[(size_t)(b * 1024 + row) * 1024 + h * 64 + nt * 16 + lm] = f2bf(oacc[nt][r]);
        }
}

// ---------------------------------------------------------------------------
extern "C" void kernel_launch(void* const* d_in, const int* in_sizes, int n_in,
                              void* d_out, int out_size, void* d_ws, size_t ws_size,
                              hipStream_t stream) {
    const float* x    = (const float*)d_in[0];   // fp32 per reference
    const int*   mask = (const int*)d_in[1];
    const float* wqkv = (const float*)d_in[2];
    const float* wout = (const float*)d_in[3];
    const float* bout = (const float*)d_in[4];

    float* out  = (float*)d_out;                    // [8192][1024] fp32
    float* attn = out + (size_t)8192 * 1024;        // [128][1024][1024] fp32

    // workspace layout (~92 MB). vt aliases xbf (dead after gemm_qkv);
    // invl aliases wqkvT (dead after gemm_qkv).
    char* ws = (char*)d_ws;
    u16* xbf   = (u16*)(ws);                        // 16,777,216 B
    u16* vt    = xbf;                               // reuse after gemm_qkv
    u16* qkv   = (u16*)(ws + 16777216);             // 50,331,648 B
    u16* o_ws  = (u16*)(ws + 67108864);             // 16,777,216 B
    u16* wqkvT = (u16*)(ws + 83886080);             //  6,291,456 B
    float* invl = (float*)(ws + 83886080);          //  524,288 B (aliases wqkvT)
    u16* woutT = (u16*)(ws + 90177536);             //  2,097,152 B

    cast_f32_bf16<<<dim3(8192), 256, 0, stream>>>(x, xbf, 8388608);
    transpose_f32_bf16<<<dim3(48, 16), 256, 0, stream>>>(wqkv, wqkvT, 1024, 3072);
    transpose_f32_bf16<<<dim3(16, 16), 256, 0, stream>>>(wout, woutT, 1024, 1024);
    gemm_bt<false, false><<<dim3(24, 64), 256, 0, stream>>>(xbf, wqkvT, nullptr, qkv, 8192, 3072, 1024);
    make_vt<<<dim3(16, 128), 256, 0, stream>>>(qkv, vt);
    attn_lsum<<<dim3(16, 128), 256, 0, stream>>>(qkv, mask, invl);
    attn_pv<<<dim3(16, 128), 256, 0, stream>>>(qkv, vt, mask, invl, attn, o_ws);
    gemm_bt<true, true><<<dim3(8, 64), 256, 0, stream>>>(o_ws, woutT, bout, out, 8192, 1024, 1024);
}